// Round 1
// baseline (103.930 us; speedup 1.0000x reference)
//
#include <hip/hip_runtime.h>
#include <utility>
#include <math.h>

// Problem constants (fixed by the reference)
#define BATCH     128
#define IN_DIM    784
#define HIDDEN    100
#define MM        10      // M_MODES
#define NPH       5       // N_PHOT
#define NSTATES   2002    // C(14,5)
#define NCLASSES  10

// ---------------------------------------------------------------------------
// Kernel A: per batch row b:
//   h = sigmoid(x[b] @ W1^T + b1)          (100 dots of length 784)
//   theta[q] = sum_g h[g*10+q]
//   phase[q] = exp(i*theta[q])
//   A[p][c]  = sum_q WR[p][q] * phase[q] * WL[q][2c]   (10x5 complex)
// writes A (float2 x 50) to ws, seeds out with b2.
// ---------------------------------------------------------------------------
__global__ __launch_bounds__(256) void qc_stageA(
    const float* __restrict__ x, const float* __restrict__ W1,
    const float* __restrict__ b1,
    const float* __restrict__ wl_re, const float* __restrict__ wl_im,
    const float* __restrict__ wr_re, const float* __restrict__ wr_im,
    const float* __restrict__ b2,
    float* __restrict__ A_ws, float* __restrict__ out)
{
    __shared__ __align__(16) float xs[IN_DIM];
    __shared__ float part[200];
    __shared__ float hs[HIDDEN];
    __shared__ float phc[MM], phs_[MM];
    __shared__ float plr[50], pli[50];

    const int b   = blockIdx.x;
    const int tid = threadIdx.x;

    for (int i = tid; i < IN_DIM; i += 256) xs[i] = x[b * IN_DIM + i];
    if (tid < NCLASSES) out[b * NCLASSES + tid] = b2[tid];   // init (b2=bias)
    __syncthreads();

    // split-K GEMM: 2 threads per output row, 392 elems each, float4 x 4 accs
    if (tid < 200) {
        const int j = tid >> 1, half = tid & 1;
        const float* wr_ = W1 + j * IN_DIM + half * 392;
        const float* xr  = xs + half * 392;
        float4 acc = make_float4(0.f, 0.f, 0.f, 0.f);
        #pragma unroll 4
        for (int i = 0; i < 392; i += 4) {
            float4 w  = *(const float4*)(wr_ + i);
            float4 xv = *(const float4*)(xr + i);
            acc.x += w.x * xv.x; acc.y += w.y * xv.y;
            acc.z += w.z * xv.z; acc.w += w.w * xv.w;
        }
        part[tid] = (acc.x + acc.y) + (acc.z + acc.w);
    }
    __syncthreads();

    if (tid < HIDDEN) {
        float t = part[2 * tid] + part[2 * tid + 1] + b1[tid];
        hs[tid] = 1.0f / (1.0f + expf(-t));
    }
    __syncthreads();

    if (tid < MM) {
        float th = 0.f;
        #pragma unroll
        for (int g = 0; g < MM; ++g) th += hs[g * MM + tid];
        float sv, cv;
        sincosf(th, &sv, &cv);
        phc[tid] = cv; phs_[tid] = sv;
    }
    __syncthreads();

    if (tid < 50) {   // PL[q][c] = phase[q] * WL[q][2c]
        const int q = tid / 5, c = tid % 5;
        const float lr = wl_re[q * MM + 2 * c], li = wl_im[q * MM + 2 * c];
        plr[tid] = phc[q] * lr - phs_[q] * li;
        pli[tid] = phc[q] * li + phs_[q] * lr;
    }
    __syncthreads();

    if (tid < 50) {   // A[p][c] = sum_q WR[p][q] * PL[q][c]
        const int p = tid / 5, c = tid % 5;
        float ar = 0.f, ai = 0.f;
        #pragma unroll
        for (int q = 0; q < MM; ++q) {
            const float rr = wr_re[p * MM + q], ri = wr_im[p * MM + q];
            const float br = plr[q * 5 + c],    bi = pli[q * 5 + c];
            ar += rr * br - ri * bi;
            ai += rr * bi + ri * br;
        }
        A_ws[(b * 50 + tid) * 2 + 0] = ar;
        A_ws[(b * 50 + tid) * 2 + 1] = ai;
    }
}

// ---------------------------------------------------------------------------
// Gray-code Ryser, fully template-unrolled so every index/sign is constexpr
// (keeps the 5x5 complex matrix + column sums strictly in VGPRs).
// ---------------------------------------------------------------------------
template <int K>
__device__ __forceinline__ void ryser_step(
    const float (&mr)[5][5], const float (&mi)[5][5],
    float (&cr)[5], float (&ci)[5], float& accr, float& acci)
{
    constexpr int  bit  = (K & 1) ? 0 : ((K & 2) ? 1 : ((K & 4) ? 2 : ((K & 8) ? 3 : 4)));
    constexpr int  gray = K ^ (K >> 1);
    constexpr bool addf = ((gray >> bit) & 1) != 0;
    constexpr int  pc   = ((gray) & 1) + ((gray >> 1) & 1) + ((gray >> 2) & 1) +
                          ((gray >> 3) & 1) + ((gray >> 4) & 1);
    #pragma unroll
    for (int j = 0; j < 5; ++j) {
        if (addf) { cr[j] += mr[bit][j]; ci[j] += mi[bit][j]; }
        else      { cr[j] -= mr[bit][j]; ci[j] -= mi[bit][j]; }
    }
    float pr = cr[0], pi = ci[0];
    #pragma unroll
    for (int j = 1; j < 5; ++j) {
        const float nr = pr * cr[j] - pi * ci[j];
        const float ni = pr * ci[j] + pi * cr[j];
        pr = nr; pi = ni;
    }
    if constexpr (((NPH - pc) & 1) != 0) { accr -= pr; acci -= pi; }
    else                                 { accr += pr; acci += pi; }
}

template <int... Ks>
__device__ __forceinline__ void ryser_run(
    std::integer_sequence<int, Ks...>,
    const float (&mr)[5][5], const float (&mi)[5][5],
    float (&cr)[5], float (&ci)[5], float& accr, float& acci)
{
    (ryser_step<Ks + 1>(mr, mi, cr, ci, accr, acci), ...);
}

// count of multisets of size rem from nv values: C(nv+rem-1, rem)
__device__ __forceinline__ int cwr_count(int nv, int rem)
{
    const int n = nv + rem - 1;
    if (rem == 0) return 1;
    if (rem == 1) return n;
    if (rem == 2) return (n * (n - 1)) / 2;
    if (rem == 3) return (n * (n - 1) * (n - 2)) / 6;
    return (n * (n - 1) * (n - 2) * (n - 3)) / 24;
}

// ---------------------------------------------------------------------------
// Kernel B: one thread = one (batch, state). Unrank state, 5x5 complex
// permanent via Ryser, prob = |perm|^2 / fact, reduce prob*W2 -> atomicAdd.
// grid = 128 batches * 8 chunks of 256 states.
// ---------------------------------------------------------------------------
__global__ __launch_bounds__(256) void qc_stageB(
    const float* __restrict__ A_ws, const float* __restrict__ W2,
    float* __restrict__ out)
{
    __shared__ float2 a2[50];
    __shared__ float  wsum[4][NCLASSES];

    const int tid = threadIdx.x;
    const int b   = blockIdx.x >> 3;
    const int s   = ((blockIdx.x & 7) << 8) + tid;

    if (tid < 50) a2[tid] = ((const float2*)A_ws)[b * 50 + tid];
    __syncthreads();

    const bool valid = (s < NSTATES);
    float prob = 0.f;

    if (valid) {
        // unrank s -> non-decreasing st[0..4] in [0,10)
        int st[NPH];
        {
            int r = s, prev = 0;
            #pragma unroll
            for (int pos = 0; pos < NPH; ++pos) {
                const int rem = (NPH - 1) - pos;
                int v = prev;
                for (;;) {
                    const int cnt = cwr_count(MM - v, rem);
                    if (r < cnt) break;
                    r -= cnt; ++v;
                }
                st[pos] = v; prev = v;
            }
        }

        // gather 5x5 complex submatrix into registers
        float mr[5][5], mi[5][5];
        #pragma unroll
        for (int n = 0; n < 5; ++n) {
            const int base = st[n] * 5;
            #pragma unroll
            for (int j = 0; j < 5; ++j) {
                const float2 e = a2[base + j];
                mr[n][j] = e.x; mi[n][j] = e.y;
            }
        }

        float cr[5] = {0,0,0,0,0}, ci[5] = {0,0,0,0,0};
        float accr = 0.f, acci = 0.f;
        ryser_run(std::make_integer_sequence<int, 31>{}, mr, mi, cr, ci, accr, acci);

        // fact = product of factorials of multiplicities
        float fact = 1.f; int run = 1;
        #pragma unroll
        for (int n = 1; n < 5; ++n) {
            run = (st[n] == st[n - 1]) ? (run + 1) : 1;
            fact *= (float)run;
        }
        prob = (accr * accr + acci * acci) / fact;
    }

    // per-class reduction: wave shuffle -> LDS -> one atomic per class
    #pragma unroll
    for (int c = 0; c < NCLASSES; ++c) {
        float v = 0.f;
        if (valid) v = prob * W2[c * NSTATES + s];
        #pragma unroll
        for (int off = 32; off > 0; off >>= 1) v += __shfl_down(v, off, 64);
        if ((tid & 63) == 0) wsum[tid >> 6][c] = v;
    }
    __syncthreads();
    if (tid < NCLASSES) {
        const float t = (wsum[0][tid] + wsum[1][tid]) + (wsum[2][tid] + wsum[3][tid]);
        atomicAdd(out + b * NCLASSES + tid, t);
    }
}

// ---------------------------------------------------------------------------
extern "C" void kernel_launch(void* const* d_in, const int* in_sizes, int n_in,
                              void* d_out, int out_size, void* d_ws, size_t ws_size,
                              hipStream_t stream)
{
    const float* x     = (const float*)d_in[0];
    const float* W1    = (const float*)d_in[1];
    const float* b1    = (const float*)d_in[2];
    const float* wl_re = (const float*)d_in[3];
    const float* wl_im = (const float*)d_in[4];
    const float* wr_re = (const float*)d_in[5];
    const float* wr_im = (const float*)d_in[6];
    const float* W2    = (const float*)d_in[7];
    const float* b2    = (const float*)d_in[8];
    float*       out   = (float*)d_out;
    float*       A_ws  = (float*)d_ws;   // 128*50 float2 = 51.2 KB

    qc_stageA<<<BATCH, 256, 0, stream>>>(x, W1, b1, wl_re, wl_im,
                                         wr_re, wr_im, b2, A_ws, out);
    qc_stageB<<<BATCH * 8, 256, 0, stream>>>(A_ws, W2, out);
}

// Round 2
// 101.040 us; speedup vs baseline: 1.0286x; 1.0286x over previous
//
#include <hip/hip_runtime.h>
#include <utility>
#include <math.h>

// Problem constants (fixed by the reference)
#define BATCH     128
#define IN_DIM    784
#define HIDDEN    100
#define MM        10      // M_MODES
#define NPH       5       // N_PHOT
#define NSTATES   2002    // C(14,5)
#define NCLASSES  10

// ---------------------------------------------------------------------------
// Compile-time state table: all C(14,5)=2002 multisets of 5 modes from 10,
// lexicographic (matches itertools.combinations_with_replacement). Packed:
// bits [0:20)  = 5 x 4-bit mode digits (non-decreasing)
// bits [20:27) = fact = prod(factorial(multiplicity))  (max 5! = 120)
// ---------------------------------------------------------------------------
struct StateTbl { unsigned v[NSTATES]; };

constexpr StateTbl make_state_tbl() {
    StateTbl t{};
    int idx = 0;
    for (int a = 0; a < MM; ++a)
    for (int b = a; b < MM; ++b)
    for (int c = b; c < MM; ++c)
    for (int d = c; d < MM; ++d)
    for (int e = d; e < MM; ++e) {
        int cnt[MM] = {};
        cnt[a]++; cnt[b]++; cnt[c]++; cnt[d]++; cnt[e]++;
        int f = 1;
        for (int m = 0; m < MM; ++m) {
            int kf = 1;
            for (int i = 2; i <= cnt[m]; ++i) kf *= i;
            f *= kf;
        }
        t.v[idx++] = (unsigned)a | ((unsigned)b << 4) | ((unsigned)c << 8) |
                     ((unsigned)d << 12) | ((unsigned)e << 16) |
                     ((unsigned)f << 20);
    }
    return t;
}

__device__ const StateTbl STATE_TBL = make_state_tbl();

// ---------------------------------------------------------------------------
// Kernel A: per batch row b:
//   h = sigmoid(x[b] @ W1^T + b1)          (100 dots of length 784)
//   theta[q] = sum_g h[g*10+q]
//   phase[q] = exp(i*theta[q])
//   A[p][c]  = sum_q WR[p][q] * phase[q] * WL[q][2c]   (10x5 complex)
// writes A (float2 x 50) to ws, seeds out with b2.
// ---------------------------------------------------------------------------
__global__ __launch_bounds__(256) void qc_stageA(
    const float* __restrict__ x, const float* __restrict__ W1,
    const float* __restrict__ b1,
    const float* __restrict__ wl_re, const float* __restrict__ wl_im,
    const float* __restrict__ wr_re, const float* __restrict__ wr_im,
    const float* __restrict__ b2,
    float* __restrict__ A_ws, float* __restrict__ out)
{
    __shared__ __align__(16) float xs[IN_DIM];
    __shared__ float part[200];
    __shared__ float hs[HIDDEN];
    __shared__ float phc[MM], phs_[MM];
    __shared__ float plr[50], pli[50];

    const int b   = blockIdx.x;
    const int tid = threadIdx.x;

    for (int i = tid; i < IN_DIM; i += 256) xs[i] = x[b * IN_DIM + i];
    if (tid < NCLASSES) out[b * NCLASSES + tid] = b2[tid];   // init (b2=bias)
    __syncthreads();

    // split-K GEMM: 2 threads per output row, 392 elems each, float4 x 4 accs
    if (tid < 200) {
        const int j = tid >> 1, half = tid & 1;
        const float* wr_ = W1 + j * IN_DIM + half * 392;
        const float* xr  = xs + half * 392;
        float4 acc = make_float4(0.f, 0.f, 0.f, 0.f);
        #pragma unroll 4
        for (int i = 0; i < 392; i += 4) {
            float4 w  = *(const float4*)(wr_ + i);
            float4 xv = *(const float4*)(xr + i);
            acc.x += w.x * xv.x; acc.y += w.y * xv.y;
            acc.z += w.z * xv.z; acc.w += w.w * xv.w;
        }
        part[tid] = (acc.x + acc.y) + (acc.z + acc.w);
    }
    __syncthreads();

    if (tid < HIDDEN) {
        float t = part[2 * tid] + part[2 * tid + 1] + b1[tid];
        hs[tid] = 1.0f / (1.0f + expf(-t));
    }
    __syncthreads();

    if (tid < MM) {
        float th = 0.f;
        #pragma unroll
        for (int g = 0; g < MM; ++g) th += hs[g * MM + tid];
        float sv, cv;
        sincosf(th, &sv, &cv);
        phc[tid] = cv; phs_[tid] = sv;
    }
    __syncthreads();

    if (tid < 50) {   // PL[q][c] = phase[q] * WL[q][2c]
        const int q = tid / 5, c = tid % 5;
        const float lr = wl_re[q * MM + 2 * c], li = wl_im[q * MM + 2 * c];
        plr[tid] = phc[q] * lr - phs_[q] * li;
        pli[tid] = phc[q] * li + phs_[q] * lr;
    }
    __syncthreads();

    if (tid < 50) {   // A[p][c] = sum_q WR[p][q] * PL[q][c]
        const int p = tid / 5, c = tid % 5;
        float ar = 0.f, ai = 0.f;
        #pragma unroll
        for (int q = 0; q < MM; ++q) {
            const float rr = wr_re[p * MM + q], ri = wr_im[p * MM + q];
            const float br = plr[q * 5 + c],    bi = pli[q * 5 + c];
            ar += rr * br - ri * bi;
            ai += rr * bi + ri * br;
        }
        A_ws[(b * 50 + tid) * 2 + 0] = ar;
        A_ws[(b * 50 + tid) * 2 + 1] = ai;
    }
}

// ---------------------------------------------------------------------------
// Gray-code Ryser, fully template-unrolled so every index/sign is constexpr
// (keeps the 5x5 complex matrix + column sums strictly in VGPRs).
// ---------------------------------------------------------------------------
template <int K>
__device__ __forceinline__ void ryser_step(
    const float (&mr)[5][5], const float (&mi)[5][5],
    float (&cr)[5], float (&ci)[5], float& accr, float& acci)
{
    constexpr int  bit  = (K & 1) ? 0 : ((K & 2) ? 1 : ((K & 4) ? 2 : ((K & 8) ? 3 : 4)));
    constexpr int  gray = K ^ (K >> 1);
    constexpr bool addf = ((gray >> bit) & 1) != 0;
    constexpr int  pc   = ((gray) & 1) + ((gray >> 1) & 1) + ((gray >> 2) & 1) +
                          ((gray >> 3) & 1) + ((gray >> 4) & 1);
    #pragma unroll
    for (int j = 0; j < 5; ++j) {
        if (addf) { cr[j] += mr[bit][j]; ci[j] += mi[bit][j]; }
        else      { cr[j] -= mr[bit][j]; ci[j] -= mi[bit][j]; }
    }
    float pr = cr[0], pi = ci[0];
    #pragma unroll
    for (int j = 1; j < 5; ++j) {
        const float nr = pr * cr[j] - pi * ci[j];
        const float ni = pr * ci[j] + pi * cr[j];
        pr = nr; pi = ni;
    }
    if constexpr (((NPH - pc) & 1) != 0) { accr -= pr; acci -= pi; }
    else                                 { accr += pr; acci += pi; }
}

template <int... Ks>
__device__ __forceinline__ void ryser_run(
    std::integer_sequence<int, Ks...>,
    const float (&mr)[5][5], const float (&mi)[5][5],
    float (&cr)[5], float (&ci)[5], float& accr, float& acci)
{
    (ryser_step<Ks + 1>(mr, mi, cr, ci, accr, acci), ...);
}

// ---------------------------------------------------------------------------
// Kernel B: one thread = one (batch, state). Table-lookup state, 5x5 complex
// permanent via Ryser, prob = |perm|^2 / fact, reduce prob*W2 -> atomicAdd.
// grid = 128 batches * 8 chunks of 256 states.
// ---------------------------------------------------------------------------
__global__ __launch_bounds__(256) void qc_stageB(
    const float* __restrict__ A_ws, const float* __restrict__ W2,
    float* __restrict__ out)
{
    __shared__ float2 a2[50];
    __shared__ float  wsum[4][NCLASSES];

    const int tid = threadIdx.x;
    const int b   = blockIdx.x >> 3;
    const int s   = ((blockIdx.x & 7) << 8) + tid;

    if (tid < 50) a2[tid] = ((const float2*)A_ws)[b * 50 + tid];
    __syncthreads();

    const bool valid = (s < NSTATES);
    float prob = 0.f;

    if (valid) {
        const unsigned w = STATE_TBL.v[s];   // coalesced dword load

        // gather 5x5 complex submatrix into registers (rows = state modes)
        float mr[5][5], mi[5][5];
        #pragma unroll
        for (int n = 0; n < 5; ++n) {
            const int base = ((w >> (4 * n)) & 15) * 5;
            #pragma unroll
            for (int j = 0; j < 5; ++j) {
                const float2 e = a2[base + j];
                mr[n][j] = e.x; mi[n][j] = e.y;
            }
        }

        float cr[5] = {0,0,0,0,0}, ci[5] = {0,0,0,0,0};
        float accr = 0.f, acci = 0.f;
        ryser_run(std::make_integer_sequence<int, 31>{}, mr, mi, cr, ci, accr, acci);

        const float fact = (float)(w >> 20);
        prob = (accr * accr + acci * acci) / fact;
    }

    // per-class reduction: wave shuffle -> LDS -> one atomic per class
    #pragma unroll
    for (int c = 0; c < NCLASSES; ++c) {
        float v = 0.f;
        if (valid) v = prob * W2[c * NSTATES + s];
        #pragma unroll
        for (int off = 32; off > 0; off >>= 1) v += __shfl_down(v, off, 64);
        if ((tid & 63) == 0) wsum[tid >> 6][c] = v;
    }
    __syncthreads();
    if (tid < NCLASSES) {
        const float t = (wsum[0][tid] + wsum[1][tid]) + (wsum[2][tid] + wsum[3][tid]);
        atomicAdd(out + b * NCLASSES + tid, t);
    }
}

// ---------------------------------------------------------------------------
extern "C" void kernel_launch(void* const* d_in, const int* in_sizes, int n_in,
                              void* d_out, int out_size, void* d_ws, size_t ws_size,
                              hipStream_t stream)
{
    const float* x     = (const float*)d_in[0];
    const float* W1    = (const float*)d_in[1];
    const float* b1    = (const float*)d_in[2];
    const float* wl_re = (const float*)d_in[3];
    const float* wl_im = (const float*)d_in[4];
    const float* wr_re = (const float*)d_in[5];
    const float* wr_im = (const float*)d_in[6];
    const float* W2    = (const float*)d_in[7];
    const float* b2    = (const float*)d_in[8];
    float*       out   = (float*)d_out;
    float*       A_ws  = (float*)d_ws;   // 128*50 float2 = 51.2 KB

    qc_stageA<<<BATCH, 256, 0, stream>>>(x, W1, b1, wl_re, wl_im,
                                         wr_re, wr_im, b2, A_ws, out);
    qc_stageB<<<BATCH * 8, 256, 0, stream>>>(A_ws, W2, out);
}

// Round 3
// 95.470 us; speedup vs baseline: 1.0886x; 1.0583x over previous
//
#include <hip/hip_runtime.h>
#include <utility>
#include <math.h>

// Problem constants (fixed by the reference)
#define BATCH     128
#define IN_DIM    784
#define HIDDEN    100
#define MM        10      // M_MODES
#define NPH       5       // N_PHOT
#define NSTATES   2002    // C(14,5)
#define NCLASSES  10

// ---------------------------------------------------------------------------
// Compile-time state table: all C(14,5)=2002 multisets of 5 modes from 10,
// lexicographic (matches itertools.combinations_with_replacement). Packed:
// bits [0:20)  = 5 x 4-bit mode digits (non-decreasing)
// bits [20:27) = fact = prod(factorial(multiplicity))  (max 5! = 120)
// ---------------------------------------------------------------------------
struct StateTbl { unsigned v[NSTATES]; };

constexpr StateTbl make_state_tbl() {
    StateTbl t{};
    int idx = 0;
    for (int a = 0; a < MM; ++a)
    for (int b = a; b < MM; ++b)
    for (int c = b; c < MM; ++c)
    for (int d = c; d < MM; ++d)
    for (int e = d; e < MM; ++e) {
        int cnt[MM] = {};
        cnt[a]++; cnt[b]++; cnt[c]++; cnt[d]++; cnt[e]++;
        int f = 1;
        for (int m = 0; m < MM; ++m) {
            int kf = 1;
            for (int i = 2; i <= cnt[m]; ++i) kf *= i;
            f *= kf;
        }
        t.v[idx++] = (unsigned)a | ((unsigned)b << 4) | ((unsigned)c << 8) |
                     ((unsigned)d << 12) | ((unsigned)e << 16) |
                     ((unsigned)f << 20);
    }
    return t;
}

__device__ const StateTbl STATE_TBL = make_state_tbl();

// ---------------------------------------------------------------------------
// Kernel A: per batch row b:
//   h = sigmoid(x[b] @ W1^T + b1)          (100 dots of length 784)
//   theta[q] = sum_g h[g*10+q]
//   phase[q] = exp(i*theta[q])
//   A[p][c]  = sum_q WR[p][q] * phase[q] * WL[q][2c]   (10x5 complex)
// writes A (float2 x 50) to ws, seeds out with b2.
// ---------------------------------------------------------------------------
__global__ __launch_bounds__(256) void qc_stageA(
    const float* __restrict__ x, const float* __restrict__ W1,
    const float* __restrict__ b1,
    const float* __restrict__ wl_re, const float* __restrict__ wl_im,
    const float* __restrict__ wr_re, const float* __restrict__ wr_im,
    const float* __restrict__ b2,
    float* __restrict__ A_ws, float* __restrict__ out)
{
    __shared__ __align__(16) float xs[IN_DIM];
    __shared__ float part[200];
    __shared__ float hs[HIDDEN];
    __shared__ float phc[MM], phs_[MM];
    __shared__ float plr[50], pli[50];

    const int b   = blockIdx.x;
    const int tid = threadIdx.x;

    for (int i = tid; i < IN_DIM; i += 256) xs[i] = x[b * IN_DIM + i];
    if (tid < NCLASSES) out[b * NCLASSES + tid] = b2[tid];   // init (b2=bias)
    __syncthreads();

    // split-K GEMM: 2 threads per output row, 392 elems each, float4 x 4 accs
    if (tid < 200) {
        const int j = tid >> 1, half = tid & 1;
        const float* wr_ = W1 + j * IN_DIM + half * 392;
        const float* xr  = xs + half * 392;
        float4 acc = make_float4(0.f, 0.f, 0.f, 0.f);
        #pragma unroll 4
        for (int i = 0; i < 392; i += 4) {
            float4 w  = *(const float4*)(wr_ + i);
            float4 xv = *(const float4*)(xr + i);
            acc.x += w.x * xv.x; acc.y += w.y * xv.y;
            acc.z += w.z * xv.z; acc.w += w.w * xv.w;
        }
        part[tid] = (acc.x + acc.y) + (acc.z + acc.w);
    }
    __syncthreads();

    if (tid < HIDDEN) {
        float t = part[2 * tid] + part[2 * tid + 1] + b1[tid];
        hs[tid] = 1.0f / (1.0f + expf(-t));
    }
    __syncthreads();

    if (tid < MM) {
        float th = 0.f;
        #pragma unroll
        for (int g = 0; g < MM; ++g) th += hs[g * MM + tid];
        float sv, cv;
        sincosf(th, &sv, &cv);
        phc[tid] = cv; phs_[tid] = sv;
    }
    __syncthreads();

    if (tid < 50) {   // PL[q][c] = phase[q] * WL[q][2c]
        const int q = tid / 5, c = tid % 5;
        const float lr = wl_re[q * MM + 2 * c], li = wl_im[q * MM + 2 * c];
        plr[tid] = phc[q] * lr - phs_[q] * li;
        pli[tid] = phc[q] * li + phs_[q] * lr;
    }
    __syncthreads();

    if (tid < 50) {   // A[p][c] = sum_q WR[p][q] * PL[q][c]
        const int p = tid / 5, c = tid % 5;
        float ar = 0.f, ai = 0.f;
        #pragma unroll
        for (int q = 0; q < MM; ++q) {
            const float rr = wr_re[p * MM + q], ri = wr_im[p * MM + q];
            const float br = plr[q * 5 + c],    bi = pli[q * 5 + c];
            ar += rr * br - ri * bi;
            ai += rr * bi + ri * br;
        }
        A_ws[(b * 50 + tid) * 2 + 0] = ar;
        A_ws[(b * 50 + tid) * 2 + 1] = ai;
    }
}

// ---------------------------------------------------------------------------
// Glynn formula, Gray-coded over delta_1..delta_4 (delta_0 fixed +1):
//   perm(A) = 2^{-4} * sum_{delta} (prod_k delta_k) * prod_j (sum_i delta_i A[i][j])
// 16 terms (vs Ryser's 31). Fully template-unrolled: every row index, sign,
// and +-2 coefficient is constexpr -> pure VGPR arithmetic, no spills.
// ---------------------------------------------------------------------------
template <int K>   // flip from state K-1 to K, K in [1,16)
__device__ __forceinline__ void glynn_step(
    const float (&mr)[5][5], const float (&mi)[5][5],
    float (&cr)[5], float (&ci)[5], float& accr, float& acci)
{
    constexpr int   bit  = (K & 1) ? 0 : ((K & 2) ? 1 : ((K & 4) ? 2 : 3));
    constexpr int   gray = K ^ (K >> 1);
    constexpr int   row  = bit + 1;                       // delta_row flips
    constexpr float s2   = ((gray >> bit) & 1) ? -2.0f : 2.0f;
    constexpr int   pc   = (gray & 1) + ((gray >> 1) & 1) +
                           ((gray >> 2) & 1) + ((gray >> 3) & 1);
    #pragma unroll
    for (int j = 0; j < 5; ++j) {
        cr[j] = fmaf(s2, mr[row][j], cr[j]);
        ci[j] = fmaf(s2, mi[row][j], ci[j]);
    }
    float pr = cr[0], pi = ci[0];
    #pragma unroll
    for (int j = 1; j < 5; ++j) {
        const float nr = pr * cr[j] - pi * ci[j];
        const float ni = pr * ci[j] + pi * cr[j];
        pr = nr; pi = ni;
    }
    if constexpr ((pc & 1) != 0) { accr -= pr; acci -= pi; }
    else                         { accr += pr; acci += pi; }
}

template <int... Ks>
__device__ __forceinline__ void glynn_run(
    std::integer_sequence<int, Ks...>,
    const float (&mr)[5][5], const float (&mi)[5][5],
    float (&cr)[5], float (&ci)[5], float& accr, float& acci)
{
    (glynn_step<Ks + 1>(mr, mi, cr, ci, accr, acci), ...);
}

// ---------------------------------------------------------------------------
// Kernel B: grid = 128 batches x 4 blocks; each thread handles 2 states
// (s, s+256). Per state: table lookup, 5x5 complex permanent via Glynn,
// prob = |perm|^2/(256*fact), accumulate prob*W2[c][s] into 10 registers.
// One shuffle+LDS reduction per block, one atomicAdd per (block,class).
// ---------------------------------------------------------------------------
__global__ __launch_bounds__(256) void qc_stageB(
    const float* __restrict__ A_ws, const float* __restrict__ W2,
    float* __restrict__ out)
{
    __shared__ float2 a2[50];
    __shared__ float  wsum[4][NCLASSES];

    const int tid   = threadIdx.x;
    const int b     = blockIdx.x >> 2;
    const int sbase = (blockIdx.x & 3) << 9;   // chunk of 512 states

    if (tid < 50) a2[tid] = ((const float2*)A_ws)[b * 50 + tid];
    __syncthreads();

    float cls[NCLASSES] = {0,0,0,0,0,0,0,0,0,0};

    #pragma unroll
    for (int t = 0; t < 2; ++t) {
        const int s = sbase + (t << 8) + tid;
        if (s < NSTATES) {
            const unsigned w = STATE_TBL.v[s];   // coalesced dword load

            // gather 5x5 complex submatrix into registers (rows = state modes)
            float mr[5][5], mi[5][5];
            #pragma unroll
            for (int n = 0; n < 5; ++n) {
                const int base = ((w >> (4 * n)) & 15) * 5;
                #pragma unroll
                for (int j = 0; j < 5; ++j) {
                    const float2 e = a2[base + j];
                    mr[n][j] = e.x; mi[n][j] = e.y;
                }
            }

            // init: all deltas +1 -> colsums = sum of rows, first term +prod
            float cr[5], ci[5];
            #pragma unroll
            for (int j = 0; j < 5; ++j) {
                cr[j] = ((mr[0][j] + mr[1][j]) + (mr[2][j] + mr[3][j])) + mr[4][j];
                ci[j] = ((mi[0][j] + mi[1][j]) + (mi[2][j] + mi[3][j])) + mi[4][j];
            }
            float accr = 0.f, acci = 0.f;
            {
                float pr = cr[0], pi = ci[0];
                #pragma unroll
                for (int j = 1; j < 5; ++j) {
                    const float nr = pr * cr[j] - pi * ci[j];
                    const float ni = pr * ci[j] + pi * cr[j];
                    pr = nr; pi = ni;
                }
                accr = pr; acci = pi;
            }
            glynn_run(std::make_integer_sequence<int, 15>{}, mr, mi, cr, ci, accr, acci);

            // perm = acc/16  ->  |perm|^2 = (accr^2+acci^2)/256
            const float fact = (float)(w >> 20);
            const float prob = (accr * accr + acci * acci) / (256.0f * fact);

            #pragma unroll
            for (int c = 0; c < NCLASSES; ++c)
                cls[c] = fmaf(prob, W2[c * NSTATES + s], cls[c]);
        }
    }

    // per-class reduction: wave shuffle -> LDS -> one atomic per class
    #pragma unroll
    for (int c = 0; c < NCLASSES; ++c) {
        float v = cls[c];
        #pragma unroll
        for (int off = 32; off > 0; off >>= 1) v += __shfl_down(v, off, 64);
        if ((tid & 63) == 0) wsum[tid >> 6][c] = v;
    }
    __syncthreads();
    if (tid < NCLASSES) {
        const float t = (wsum[0][tid] + wsum[1][tid]) + (wsum[2][tid] + wsum[3][tid]);
        atomicAdd(out + b * NCLASSES + tid, t);
    }
}

// ---------------------------------------------------------------------------
extern "C" void kernel_launch(void* const* d_in, const int* in_sizes, int n_in,
                              void* d_out, int out_size, void* d_ws, size_t ws_size,
                              hipStream_t stream)
{
    const float* x     = (const float*)d_in[0];
    const float* W1    = (const float*)d_in[1];
    const float* b1    = (const float*)d_in[2];
    const float* wl_re = (const float*)d_in[3];
    const float* wl_im = (const float*)d_in[4];
    const float* wr_re = (const float*)d_in[5];
    const float* wr_im = (const float*)d_in[6];
    const float* W2    = (const float*)d_in[7];
    const float* b2    = (const float*)d_in[8];
    float*       out   = (float*)d_out;
    float*       A_ws  = (float*)d_ws;   // 128*50 float2 = 51.2 KB

    qc_stageA<<<BATCH, 256, 0, stream>>>(x, W1, b1, wl_re, wl_im,
                                         wr_re, wr_im, b2, A_ws, out);
    qc_stageB<<<BATCH * 4, 256, 0, stream>>>(A_ws, W2, out);
}

// Round 4
// 87.473 us; speedup vs baseline: 1.1881x; 1.0914x over previous
//
#include <hip/hip_runtime.h>
#include <utility>
#include <math.h>

// Problem constants (fixed by the reference)
#define BATCH     128
#define IN_DIM    784
#define HIDDEN    100
#define MM        10      // M_MODES
#define NPH       5       // N_PHOT
#define NSTATES   2002    // C(14,5)
#define NCLASSES  10

// ---------------------------------------------------------------------------
// Compile-time state table: all C(14,5)=2002 multisets of 5 modes from 10,
// lexicographic (matches itertools.combinations_with_replacement). Packed:
// bits [0:20)  = 5 x 4-bit mode digits (non-decreasing)
// bits [20:27) = fact = prod(factorial(multiplicity))  (max 5! = 120)
// ---------------------------------------------------------------------------
struct StateTbl { unsigned v[NSTATES]; };

constexpr StateTbl make_state_tbl() {
    StateTbl t{};
    int idx = 0;
    for (int a = 0; a < MM; ++a)
    for (int b = a; b < MM; ++b)
    for (int c = b; c < MM; ++c)
    for (int d = c; d < MM; ++d)
    for (int e = d; e < MM; ++e) {
        int cnt[MM] = {};
        cnt[a]++; cnt[b]++; cnt[c]++; cnt[d]++; cnt[e]++;
        int f = 1;
        for (int m = 0; m < MM; ++m) {
            int kf = 1;
            for (int i = 2; i <= cnt[m]; ++i) kf *= i;
            f *= kf;
        }
        t.v[idx++] = (unsigned)a | ((unsigned)b << 4) | ((unsigned)c << 8) |
                     ((unsigned)d << 12) | ((unsigned)e << 16) |
                     ((unsigned)f << 20);
    }
    return t;
}

__device__ const StateTbl STATE_TBL = make_state_tbl();

// ---------------------------------------------------------------------------
// Glynn formula, Gray-coded over delta_1..delta_4 (delta_0 fixed +1):
//   perm(A) = 2^{-4} * sum_{delta} (prod_k delta_k) * prod_j (sum_i delta_i A[i][j])
// 16 terms. Fully template-unrolled: row index, sign, and +-2 coefficient are
// all constexpr -> pure VGPR arithmetic, no spills.
// ---------------------------------------------------------------------------
template <int K>   // flip from state K-1 to K, K in [1,16)
__device__ __forceinline__ void glynn_step(
    const float (&mr)[5][5], const float (&mi)[5][5],
    float (&cr)[5], float (&ci)[5], float& accr, float& acci)
{
    constexpr int   bit  = (K & 1) ? 0 : ((K & 2) ? 1 : ((K & 4) ? 2 : 3));
    constexpr int   gray = K ^ (K >> 1);
    constexpr int   row  = bit + 1;                       // delta_row flips
    constexpr float s2   = ((gray >> bit) & 1) ? -2.0f : 2.0f;
    constexpr int   pc   = (gray & 1) + ((gray >> 1) & 1) +
                           ((gray >> 2) & 1) + ((gray >> 3) & 1);
    #pragma unroll
    for (int j = 0; j < 5; ++j) {
        cr[j] = fmaf(s2, mr[row][j], cr[j]);
        ci[j] = fmaf(s2, mi[row][j], ci[j]);
    }
    float pr = cr[0], pi = ci[0];
    #pragma unroll
    for (int j = 1; j < 5; ++j) {
        const float nr = pr * cr[j] - pi * ci[j];
        const float ni = pr * ci[j] + pi * cr[j];
        pr = nr; pi = ni;
    }
    if constexpr ((pc & 1) != 0) { accr -= pr; acci -= pi; }
    else                         { accr += pr; acci += pi; }
}

template <int... Ks>
__device__ __forceinline__ void glynn_run(
    std::integer_sequence<int, Ks...>,
    const float (&mr)[5][5], const float (&mi)[5][5],
    float (&cr)[5], float (&ci)[5], float& accr, float& acci)
{
    (glynn_step<Ks + 1>(mr, mi, cr, ci, accr, acci), ...);
}

// ---------------------------------------------------------------------------
// Fused kernel: one block per batch row (128 blocks x 512 threads).
// Phase 1: recompute A[b] (10x5 complex) in LDS from x,W1,b1,WL,WR.
// Phase 2: 4 states per thread -> Glynn permanent -> prob -> cls[10] regs.
// Phase 3: wave shuffle + LDS reduce over 8 waves, direct store out[b][:].
// No ws traffic, no atomics, no inter-kernel barrier.
// ---------------------------------------------------------------------------
__global__ __launch_bounds__(512) void qc_fused(
    const float* __restrict__ x, const float* __restrict__ W1,
    const float* __restrict__ b1,
    const float* __restrict__ wl_re, const float* __restrict__ wl_im,
    const float* __restrict__ wr_re, const float* __restrict__ wr_im,
    const float* __restrict__ W2, const float* __restrict__ b2,
    float* __restrict__ out)
{
    __shared__ __align__(16) float xs[IN_DIM];
    __shared__ float  part[400];
    __shared__ float  hs[HIDDEN];
    __shared__ float  phc[MM], phs_[MM];
    __shared__ float  plr[50], pli[50];
    __shared__ float2 a2[50];
    __shared__ float  wsum[8][NCLASSES];

    const int b   = blockIdx.x;
    const int tid = threadIdx.x;

    // ---- Phase 1: A[b] ----
    for (int i = tid; i < IN_DIM; i += 512) xs[i] = x[b * IN_DIM + i];
    __syncthreads();

    // GEMM: 4 threads per hidden row, 196 elems each (float4 x 49)
    if (tid < 400) {
        const int j = tid >> 2, q = tid & 3;
        const float* wr_ = W1 + j * IN_DIM + q * 196;
        const float* xr  = xs + q * 196;
        float4 acc = make_float4(0.f, 0.f, 0.f, 0.f);
        #pragma unroll 7
        for (int i = 0; i < 196; i += 4) {
            float4 w  = *(const float4*)(wr_ + i);
            float4 xv = *(const float4*)(xr + i);
            acc.x += w.x * xv.x; acc.y += w.y * xv.y;
            acc.z += w.z * xv.z; acc.w += w.w * xv.w;
        }
        part[tid] = (acc.x + acc.y) + (acc.z + acc.w);
    }
    __syncthreads();

    if (tid < HIDDEN) {
        float t = (part[4 * tid] + part[4 * tid + 1]) +
                  (part[4 * tid + 2] + part[4 * tid + 3]) + b1[tid];
        hs[tid] = 1.0f / (1.0f + expf(-t));
    }
    __syncthreads();

    if (tid < MM) {
        float th = 0.f;
        #pragma unroll
        for (int g = 0; g < MM; ++g) th += hs[g * MM + tid];
        float sv, cv;
        sincosf(th, &sv, &cv);
        phc[tid] = cv; phs_[tid] = sv;
    }
    __syncthreads();

    if (tid < 50) {   // PL[q][c] = phase[q] * WL[q][2c]
        const int q = tid / 5, c = tid % 5;
        const float lr = wl_re[q * MM + 2 * c], li = wl_im[q * MM + 2 * c];
        plr[tid] = phc[q] * lr - phs_[q] * li;
        pli[tid] = phc[q] * li + phs_[q] * lr;
    }
    __syncthreads();

    if (tid < 50) {   // A[p][c] = sum_q WR[p][q] * PL[q][c]
        const int p = tid / 5, c = tid % 5;
        float ar = 0.f, ai = 0.f;
        #pragma unroll
        for (int q = 0; q < MM; ++q) {
            const float rr = wr_re[p * MM + q], ri = wr_im[p * MM + q];
            const float br = plr[q * 5 + c],    bi = pli[q * 5 + c];
            ar += rr * br - ri * bi;
            ai += rr * bi + ri * br;
        }
        a2[tid] = make_float2(ar, ai);
    }
    __syncthreads();

    // ---- Phase 2: permanents + class accumulation ----
    float cls[NCLASSES] = {0,0,0,0,0,0,0,0,0,0};

    #pragma unroll
    for (int t = 0; t < 4; ++t) {
        const int s = (t << 9) + tid;
        if (s < NSTATES) {
            const unsigned w = STATE_TBL.v[s];   // coalesced dword load

            // gather 5x5 complex submatrix into registers (rows = state modes)
            float mr[5][5], mi[5][5];
            #pragma unroll
            for (int n = 0; n < 5; ++n) {
                const int base = ((w >> (4 * n)) & 15) * 5;
                #pragma unroll
                for (int j = 0; j < 5; ++j) {
                    const float2 e = a2[base + j];
                    mr[n][j] = e.x; mi[n][j] = e.y;
                }
            }

            // init: all deltas +1 -> colsums = sum of rows, first term +prod
            float cr[5], ci[5];
            #pragma unroll
            for (int j = 0; j < 5; ++j) {
                cr[j] = ((mr[0][j] + mr[1][j]) + (mr[2][j] + mr[3][j])) + mr[4][j];
                ci[j] = ((mi[0][j] + mi[1][j]) + (mi[2][j] + mi[3][j])) + mi[4][j];
            }
            float accr, acci;
            {
                float pr = cr[0], pi = ci[0];
                #pragma unroll
                for (int j = 1; j < 5; ++j) {
                    const float nr = pr * cr[j] - pi * ci[j];
                    const float ni = pr * ci[j] + pi * cr[j];
                    pr = nr; pi = ni;
                }
                accr = pr; acci = pi;
            }
            glynn_run(std::make_integer_sequence<int, 15>{}, mr, mi, cr, ci, accr, acci);

            // perm = acc/16  ->  |perm|^2 = (accr^2+acci^2)/256
            const float fact = (float)(w >> 20);
            const float prob = (accr * accr + acci * acci) / (256.0f * fact);

            #pragma unroll
            for (int c = 0; c < NCLASSES; ++c)
                cls[c] = fmaf(prob, W2[c * NSTATES + s], cls[c]);
        }
    }

    // ---- Phase 3: reduce 8 waves -> direct store (no atomics) ----
    #pragma unroll
    for (int c = 0; c < NCLASSES; ++c) {
        float v = cls[c];
        #pragma unroll
        for (int off = 32; off > 0; off >>= 1) v += __shfl_down(v, off, 64);
        if ((tid & 63) == 0) wsum[tid >> 6][c] = v;
    }
    __syncthreads();
    if (tid < NCLASSES) {
        float t = 0.f;
        #pragma unroll
        for (int wv = 0; wv < 8; ++wv) t += wsum[wv][tid];
        out[b * NCLASSES + tid] = t + b2[tid];
    }
}

// ---------------------------------------------------------------------------
extern "C" void kernel_launch(void* const* d_in, const int* in_sizes, int n_in,
                              void* d_out, int out_size, void* d_ws, size_t ws_size,
                              hipStream_t stream)
{
    const float* x     = (const float*)d_in[0];
    const float* W1    = (const float*)d_in[1];
    const float* b1    = (const float*)d_in[2];
    const float* wl_re = (const float*)d_in[3];
    const float* wl_im = (const float*)d_in[4];
    const float* wr_re = (const float*)d_in[5];
    const float* wr_im = (const float*)d_in[6];
    const float* W2    = (const float*)d_in[7];
    const float* b2    = (const float*)d_in[8];
    float*       out   = (float*)d_out;

    qc_fused<<<BATCH, 512, 0, stream>>>(x, W1, b1, wl_re, wl_im,
                                        wr_re, wr_im, W2, b2, out);
}